// Round 1
// baseline (116126.807 us; speedup 1.0000x reference)
//
#include <hip/hip_runtime.h>
#include <hip/hip_cooperative_groups.h>
#include <math.h>

namespace cg = cooperative_groups;

#define Bz  64
#define Ez  512
#define Hz  1024
#define SLz 128
#define TLz 128
#define NWG 512     // logical workgroups per layer phase (4096 rows / 8 rows-per-WG)
#define TPB 128     // 2 waves per WG

// ---------------------------------------------------------------------------
// One LSTM layer, one timestep.
// Grid-logical layout: WG wg owns hidden units {2wg, 2wg+1} x all 4 gates
// (8 weight rows). Wave wv (0/1) computes gates {2wv, 2wv+1} for both hidden
// units: 4 rows, lanes = batch. Row indices are wave-uniform (readfirstlane)
// so weight loads can become s_loads; x/h are read as coalesced vector loads
// from transposed [K][B] state buffers (or gathered embedding rows).
// Gate exchange + cell update fused via LDS.
// ---------------------------------------------------------------------------
__device__ void lstm_phase(int nblocks,
    const float* __restrict__ embed, const int* __restrict__ ids,
    int ids_stride, int ids_off,
    const float* __restrict__ xT, int Dx,
    const float* __restrict__ Wih, const float* __restrict__ Whh,
    const float* __restrict__ bias,
    const float* __restrict__ hin, float* __restrict__ hout,
    float* __restrict__ cst)
{
    __shared__ float z_lds[8 * Bz];
    const int tid  = threadIdx.x;
    const int lane = tid & 63;
    const int wv   = __builtin_amdgcn_readfirstlane(tid >> 6);

    for (int wg = blockIdx.x; wg < NWG; wg += nblocks) {
        const int hu0 = wg * 2;
        const int r0 = (2 * wv + 0) * Hz + hu0;   // gate 2wv  , hu0
        const int r1 = r0 + 1;                    // gate 2wv  , hu0+1
        const int r2 = (2 * wv + 1) * Hz + hu0;   // gate 2wv+1, hu0
        const int r3 = r2 + 1;                    // gate 2wv+1, hu0+1

        float acc0 = bias[r0], acc1 = bias[r1], acc2 = bias[r2], acc3 = bias[r3];

        // ---- x contribution (K = Dx) ----
        const float* xrow = nullptr;
        if (ids) {
            const int idx = ids[lane * ids_stride + ids_off];
            xrow = embed + (size_t)idx * Dx;
        }
        const float* wa = Wih + (size_t)r0 * Dx;
        const float* wb = Wih + (size_t)r1 * Dx;
        const float* wc = Wih + (size_t)r2 * Dx;
        const float* wd = Wih + (size_t)r3 * Dx;
        for (int k0 = 0; k0 < Dx; k0 += 16) {
            float xv[16];
            if (ids) {
                #pragma unroll
                for (int j = 0; j < 16; ++j) xv[j] = xrow[k0 + j];
            } else {
                #pragma unroll
                for (int j = 0; j < 16; ++j) xv[j] = xT[(size_t)(k0 + j) * Bz + lane];
            }
            #pragma unroll
            for (int j = 0; j < 16; ++j) {
                acc0 += wa[k0 + j] * xv[j];
                acc1 += wb[k0 + j] * xv[j];
                acc2 += wc[k0 + j] * xv[j];
                acc3 += wd[k0 + j] * xv[j];
            }
        }

        // ---- h contribution (K = Hz) ----
        const float* ua = Whh + (size_t)r0 * Hz;
        const float* ub = Whh + (size_t)r1 * Hz;
        const float* uc = Whh + (size_t)r2 * Hz;
        const float* ud = Whh + (size_t)r3 * Hz;
        for (int k0 = 0; k0 < Hz; k0 += 16) {
            float xv[16];
            #pragma unroll
            for (int j = 0; j < 16; ++j) xv[j] = hin[(size_t)(k0 + j) * Bz + lane];
            #pragma unroll
            for (int j = 0; j < 16; ++j) {
                acc0 += ua[k0 + j] * xv[j];
                acc1 += ub[k0 + j] * xv[j];
                acc2 += uc[k0 + j] * xv[j];
                acc3 += ud[k0 + j] * xv[j];
            }
        }

        // ---- gate exchange + cell update ----
        z_lds[((2 * wv + 0) * 2 + 0) * Bz + lane] = acc0;
        z_lds[((2 * wv + 0) * 2 + 1) * Bz + lane] = acc1;
        z_lds[((2 * wv + 1) * 2 + 0) * Bz + lane] = acc2;
        z_lds[((2 * wv + 1) * 2 + 1) * Bz + lane] = acc3;
        __syncthreads();
        {
            const int b  = tid & 63;
            const int hi = tid >> 6;                        // 0..1
            const float zi = z_lds[(0 * 2 + hi) * Bz + b];  // i
            const float zf = z_lds[(1 * 2 + hi) * Bz + b];  // f
            const float zg = z_lds[(2 * 2 + hi) * Bz + b];  // g
            const float zo = z_lds[(3 * 2 + hi) * Bz + b];  // o
            const int hidx = (hu0 + hi) * Bz + b;           // [H][B] transposed state
            const float cold = cst[hidx];
            const float ig = 1.0f / (1.0f + expf(-zi));
            const float fg = 1.0f / (1.0f + expf(-zf));
            const float gg = tanhf(zg);
            const float og = 1.0f / (1.0f + expf(-zo));
            const float cnew = fg * cold + ig * gg;
            cst[hidx]  = cnew;
            hout[hidx] = og * tanhf(cnew);
        }
        __syncthreads();
    }
}

// logits_T[j][b] = linb[j] + sum_k linW[j][k] * h1_T[k][b]
__device__ void head_phase(int nblocks,
    const float* __restrict__ linW, const float* __restrict__ linb,
    const float* __restrict__ h1T, float* __restrict__ logitsT)
{
    const int tid  = threadIdx.x;
    const int lane = tid & 63;
    const int wv   = __builtin_amdgcn_readfirstlane(tid >> 6);
    for (int wg = blockIdx.x; wg < NWG; wg += nblocks) {
        const int row = wg * 2 + wv;   // 0..1023
        float acc = linb[row];
        const float* wr = linW + (size_t)row * Hz;
        for (int k0 = 0; k0 < Hz; k0 += 16) {
            float xv[16];
            #pragma unroll
            for (int j = 0; j < 16; ++j) xv[j] = h1T[(size_t)(k0 + j) * Bz + lane];
            #pragma unroll
            for (int j = 0; j < 16; ++j) acc += wr[k0 + j] * xv[j];
        }
        logitsT[(size_t)row * Bz + lane] = acc;
    }
}

// Per-batch-row log-softmax, greedy argmax feedback, NLL accumulation.
__device__ void softmax_phase(int nblocks, int t,
    const float* __restrict__ logitsT, const int* __restrict__ tag_ids,
    float* __restrict__ out, int* __restrict__ deint, float* __restrict__ loss)
{
    __shared__ float s_v[TPB];
    __shared__ int   s_i[TPB];
    __shared__ float s_r[TPB];
    __shared__ float s_tgt[1];
    const int tid = threadIdx.x;
    for (int wg = blockIdx.x; wg < NWG; wg += nblocks) {
        if (wg < Bz) {
            const int b = wg;
            float v[8];
            #pragma unroll
            for (int jj = 0; jj < 8; ++jj)
                v[jj] = logitsT[(size_t)(tid + jj * TPB) * Bz + b];

            // argmax (first-max semantics: ties -> smaller index)
            float bv = v[0]; int bi = tid;
            #pragma unroll
            for (int jj = 1; jj < 8; ++jj) {
                const int j = tid + jj * TPB;   // ascending within thread
                if (v[jj] > bv) { bv = v[jj]; bi = j; }
            }
            s_v[tid] = bv; s_i[tid] = bi;
            __syncthreads();
            for (int s = TPB / 2; s > 0; s >>= 1) {
                if (tid < s) {
                    const float v2 = s_v[tid + s]; const int i2 = s_i[tid + s];
                    if (v2 > s_v[tid] || (v2 == s_v[tid] && i2 < s_i[tid])) {
                        s_v[tid] = v2; s_i[tid] = i2;
                    }
                }
                __syncthreads();
            }
            const float gmax = s_v[0];
            const int   gam  = s_i[0];

            float ls = 0.0f;
            #pragma unroll
            for (int jj = 0; jj < 8; ++jj) ls += expf(v[jj] - gmax);
            s_r[tid] = ls;
            __syncthreads();
            for (int s = TPB / 2; s > 0; s >>= 1) {
                if (tid < s) s_r[tid] += s_r[tid + s];
                __syncthreads();
            }
            const float lse = gmax + logf(s_r[0]);

            float* orow = out + ((size_t)t * Bz + b) * Hz;
            #pragma unroll
            for (int jj = 0; jj < 8; ++jj) orow[tid + jj * TPB] = v[jj] - lse;

            const int tgt = tag_ids[b * TLz + t];
            #pragma unroll
            for (int jj = 0; jj < 8; ++jj)
                if (tid + jj * TPB == tgt) s_tgt[0] = v[jj];
            __syncthreads();
            if (tid == 0) {
                deint[b] = gam;
                if (tgt != 0) {  // PAD == 0
                    int cnt = 0;
                    for (int bb = 0; bb < Bz; ++bb)
                        cnt += (tag_ids[bb * TLz + t] != 0) ? 1 : 0;
                    if (cnt < 1) cnt = 1;
                    atomicAdd(loss, (lse - s_tgt[0]) / (float)cnt);
                }
            }
            __syncthreads();
        }
    }
}

__global__ void __launch_bounds__(TPB) seq2seq_kernel(
    const int* __restrict__ input_ids, const int* __restrict__ tag_ids,
    const float* __restrict__ enc_embed,
    const float* __restrict__ eW0, const float* __restrict__ eU0, const float* __restrict__ eb0,
    const float* __restrict__ eW1, const float* __restrict__ eU1, const float* __restrict__ eb1,
    const float* __restrict__ dec_embed,
    const float* __restrict__ dW0, const float* __restrict__ dU0, const float* __restrict__ db0,
    const float* __restrict__ dW1, const float* __restrict__ dU1, const float* __restrict__ db1,
    const float* __restrict__ linW, const float* __restrict__ linb,
    float* __restrict__ out, float* __restrict__ wsf)
{
    cg::grid_group grid = cg::this_grid();
    const int nblocks = gridDim.x;

    // ws layout (floats), states transposed [H][B]:
    float* h0a = wsf;
    float* c0  = wsf + 65536;
    float* h1a = wsf + 131072;
    float* c1  = wsf + 196608;
    float* h0b = wsf + 262144;
    float* h1b = wsf + 327680;
    float* logitsT = wsf + 393216;           // [1024][64]
    int*   deint   = (int*)(wsf + 458752);   // [64]
    float* loss    = out + (size_t)TLz * Bz * Hz;

    // init: zero h0a,c0,h1a,c1 (contiguous 262144 floats), deint, loss
    {
        const int gsz = nblocks * TPB;
        for (int i = blockIdx.x * TPB + threadIdx.x; i < 262144 + Bz + 1; i += gsz) {
            if (i < 262144)            wsf[i] = 0.0f;
            else if (i < 262144 + Bz)  deint[i - 262144] = 0;
            else                       *loss = 0.0f;
        }
    }
    grid.sync();

    float* h0c = h0a; float* h0n = h0b;
    float* h1c = h1a; float* h1n = h1b;

    // ---------------- encoder ----------------
    for (int t = 0; t < SLz; ++t) {
        lstm_phase(nblocks, enc_embed, input_ids, SLz, t, nullptr, Ez,
                   eW0, eU0, eb0, h0c, h0n, c0);
        grid.sync();
        lstm_phase(nblocks, nullptr, nullptr, 0, 0, h0n, Hz,
                   eW1, eU1, eb1, h1c, h1n, c1);
        grid.sync();
        float* tmp = h0c; h0c = h0n; h0n = tmp;
        tmp = h1c; h1c = h1n; h1n = tmp;
    }

    // ---------------- decoder ----------------
    for (int t = 0; t < TLz; ++t) {
        lstm_phase(nblocks, dec_embed, deint, 1, 0, nullptr, Ez,
                   dW0, dU0, db0, h0c, h0n, c0);
        grid.sync();
        lstm_phase(nblocks, nullptr, nullptr, 0, 0, h0n, Hz,
                   dW1, dU1, db1, h1c, h1n, c1);
        grid.sync();
        head_phase(nblocks, linW, linb, h1n, logitsT);
        grid.sync();
        softmax_phase(nblocks, t, logitsT, tag_ids, out, deint, loss);
        grid.sync();
        float* tmp = h0c; h0c = h0n; h0n = tmp;
        tmp = h1c; h1c = h1n; h1n = tmp;
    }
}

extern "C" void kernel_launch(void* const* d_in, const int* in_sizes, int n_in,
                              void* d_out, int out_size, void* d_ws, size_t ws_size,
                              hipStream_t stream) {
    const int*   input_ids = (const int*)d_in[0];
    const int*   tag_ids   = (const int*)d_in[1];
    const float* enc_embed = (const float*)d_in[2];
    const float* eW0 = (const float*)d_in[3];
    const float* eU0 = (const float*)d_in[4];
    const float* eb0 = (const float*)d_in[5];
    const float* eW1 = (const float*)d_in[6];
    const float* eU1 = (const float*)d_in[7];
    const float* eb1 = (const float*)d_in[8];
    const float* dec_embed = (const float*)d_in[9];
    const float* dW0 = (const float*)d_in[10];
    const float* dU0 = (const float*)d_in[11];
    const float* db0 = (const float*)d_in[12];
    const float* dW1 = (const float*)d_in[13];
    const float* dU1 = (const float*)d_in[14];
    const float* db1 = (const float*)d_in[15];
    const float* linW = (const float*)d_in[16];
    const float* linb = (const float*)d_in[17];
    float* out = (float*)d_out;
    float* wsf = (float*)d_ws;

    int maxb = 2;
    (void)hipOccupancyMaxActiveBlocksPerMultiprocessor(&maxb, seq2seq_kernel, TPB, 0);
    if (maxb < 1) maxb = 1;
    int grid = NWG;
    if (maxb * 256 < grid) grid = maxb * 256;

    void* args[] = { &input_ids, &tag_ids, &enc_embed,
                     &eW0, &eU0, &eb0, &eW1, &eU1, &eb1,
                     &dec_embed, &dW0, &dU0, &db0, &dW1, &dU1, &db1,
                     &linW, &linb, &out, &wsf };
    (void)hipLaunchCooperativeKernel(seq2seq_kernel, dim3(grid), dim3(TPB),
                                     args, 0u, stream);
}

// Round 2
// 63224.261 us; speedup vs baseline: 1.8367x; 1.8367x over previous
//
#include <hip/hip_runtime.h>
#include <hip/hip_cooperative_groups.h>
#include <math.h>

namespace cg = cooperative_groups;

#define Bz  64
#define Ez  512
#define Hz  1024
#define SLz 128
#define TLz 128
#define NBLK 256
#define TPB 512

// packed x layout: element (k, b) at ((k>>2)<<8) + (b<<2) + (k&3)
#define XPK(k, b) ((((k) >> 2) << 8) + ((b) << 2) + ((k) & 3))

// ---------------------------------------------------------------------------
// One LSTM layer, one timestep, one unit-group (4 hidden units) per block.
// 8 waves: wave w -> half = w>>2 (K split in 2), ur = w&3 (unit in group).
// Each wave: 4 rows (unit ur across gates i,f,g,o) x K/2.
// Weights staged global->LDS (vector path, coalesced dwordx4), read back as
// wave-uniform ds_read_b128 broadcasts. x read as coalesced dwordx4 from the
// 4-k-packed state buffers (or gathered embedding rows).
// ---------------------------------------------------------------------------
__device__ __forceinline__ void lstm_phase(
    float* __restrict__ smem_f,
    const float* __restrict__ embed, const int* __restrict__ ids,
    int ids_stride, int ids_off,
    const float* __restrict__ xPK, int Dx,
    const float* __restrict__ Wih, const float* __restrict__ Whh,
    const float* __restrict__ bias,
    const float* __restrict__ hinPK, float* __restrict__ houtPK,
    float* __restrict__ cst)
{
    float* wt = smem_f;          // [2][16][64] staged weight tiles
    float* zb = smem_f + 2048;   // [2][16][64] partial z
    const int tid  = threadIdx.x;
    const int lane = tid & 63;
    const int wv   = tid >> 6;        // 0..7
    const int half = wv >> 2;         // K-split half
    const int ur   = wv & 3;          // unit within group
    const int hu0  = blockIdx.x << 2; // unit-group base
    const int Kh   = (Dx + Hz) >> 1;

    // per-lane embedding row base (layer-0 path)
    const float* xrow = nullptr;
    if (embed) {
        const int idx = ids[lane * ids_stride + ids_off];
        xrow = embed + (size_t)idx * Dx;
    }

    float acc0 = 0.f, acc1 = 0.f, acc2 = 0.f, acc3 = 0.f;

    // fixed staging assignment: thread stages 4 floats of one row-tile
    const int sh   = tid >> 8;        // staging half
    const int sidx = tid & 255;
    const int sr   = sidx >> 4;       // row_local = g*4+u
    const int sg   = sr >> 2, su = sr & 3;
    const int srow = (sg << 10) + hu0 + su;   // global weight row
    const int skl  = (sidx & 15) << 2;

    const int wb0 = (half << 10) + (ur << 6);        // gate 0 row base in wt
    const int wb1 = wb0 + 256;
    const int wb2 = wb0 + 512;
    const int wb3 = wb0 + 768;

    for (int kt = 0; kt < Kh; kt += 64) {
        // ---- stage both halves' 64-k weight tiles (vector loads) ----
        {
            const int kg = sh * Kh + kt + skl;
            const float* src = (kg < Dx)
                ? (Wih + (size_t)srow * Dx + kg)
                : (Whh + ((size_t)srow << 10) + (kg - Dx));
            *(float4*)&wt[(sh << 10) + (sr << 6) + skl] = *(const float4*)src;
        }
        __syncthreads();

        const int kgb = half * Kh + kt;

#define FMA16(KL, XV)                                                   \
        {                                                               \
            const float4 w0 = *(const float4*)&wt[wb0 + (KL)];          \
            const float4 w1 = *(const float4*)&wt[wb1 + (KL)];          \
            const float4 w2 = *(const float4*)&wt[wb2 + (KL)];          \
            const float4 w3 = *(const float4*)&wt[wb3 + (KL)];          \
            acc0 = fmaf(w0.x, (XV).x, acc0); acc0 = fmaf(w0.y, (XV).y, acc0); \
            acc0 = fmaf(w0.z, (XV).z, acc0); acc0 = fmaf(w0.w, (XV).w, acc0); \
            acc1 = fmaf(w1.x, (XV).x, acc1); acc1 = fmaf(w1.y, (XV).y, acc1); \
            acc1 = fmaf(w1.z, (XV).z, acc1); acc1 = fmaf(w1.w, (XV).w, acc1); \
            acc2 = fmaf(w2.x, (XV).x, acc2); acc2 = fmaf(w2.y, (XV).y, acc2); \
            acc2 = fmaf(w2.z, (XV).z, acc2); acc2 = fmaf(w2.w, (XV).w, acc2); \
            acc3 = fmaf(w3.x, (XV).x, acc3); acc3 = fmaf(w3.y, (XV).y, acc3); \
            acc3 = fmaf(w3.z, (XV).z, acc3); acc3 = fmaf(w3.w, (XV).w, acc3); \
        }

        if (kgb < Dx) {
            if (embed) {
                #pragma unroll 4
                for (int kl = 0; kl < 64; kl += 4) {
                    const float4 xv = *(const float4*)(xrow + kgb + kl);
                    FMA16(kl, xv);
                }
            } else {
                #pragma unroll 4
                for (int kl = 0; kl < 64; kl += 4) {
                    const int k = kgb + kl;
                    const float4 xv = *(const float4*)(xPK + ((k >> 2) << 8) + (lane << 2));
                    FMA16(kl, xv);
                }
            }
        } else {
            #pragma unroll 4
            for (int kl = 0; kl < 64; kl += 4) {
                const int k = kgb + kl - Dx;
                const float4 xv = *(const float4*)(hinPK + ((k >> 2) << 8) + (lane << 2));
                FMA16(kl, xv);
            }
        }
#undef FMA16
        __syncthreads();
    }

    // partial z to LDS: zb[half][g*4+ur][lane]
    zb[(half << 10) + (0 << 8) + (ur << 6) + lane] = acc0;
    zb[(half << 10) + (1 << 8) + (ur << 6) + lane] = acc1;
    zb[(half << 10) + (2 << 8) + (ur << 6) + lane] = acc2;
    zb[(half << 10) + (3 << 8) + (ur << 6) + lane] = acc3;
    __syncthreads();

    if (tid < 256) {
        const int u = tid >> 6, b = tid & 63;
        const int base = (u << 6) + b;
        const float zi = zb[base]         + zb[1024 + base]         + bias[(hu0 + u)];
        const float zf = zb[256 + base]   + zb[1024 + 256 + base]   + bias[1024 + (hu0 + u)];
        const float zg = zb[512 + base]   + zb[1024 + 512 + base]   + bias[2048 + (hu0 + u)];
        const float zo = zb[768 + base]   + zb[1024 + 768 + base]   + bias[3072 + (hu0 + u)];
        const int hk = hu0 + u;
        const float cold = cst[(hk << 6) + b];
        const float ig = 1.0f / (1.0f + expf(-zi));
        const float fg = 1.0f / (1.0f + expf(-zf));
        const float gg = tanhf(zg);
        const float og = 1.0f / (1.0f + expf(-zo));
        const float cnew = fg * cold + ig * gg;
        cst[(hk << 6) + b] = cnew;
        houtPK[XPK(hk, b)] = og * tanhf(cnew);
    }
}

// logits[row][b] = linb[row] + sum_k linW[row][k] * h1[k][b]
// block = 4 rows; 8 waves K-split 8; LDS staging of the 4 full weight rows.
__device__ __forceinline__ void head_phase(
    float* __restrict__ smem_f,
    const float* __restrict__ linW, const float* __restrict__ linb,
    const float* __restrict__ h1PK, float* __restrict__ logits)
{
    float* wt = smem_f;          // [4][1024]
    float* zb = smem_f + 4096;   // [8][4][64]
    const int tid = threadIdx.x, lane = tid & 63, wv = tid >> 6;
    const int hu0 = blockIdx.x << 2;
    {
        const int f0 = tid << 3;               // 8 floats per thread
        const int r = f0 >> 10, k0 = f0 & 1023;
        const float* src = linW + (((size_t)(hu0 + r)) << 10) + k0;
        *(float4*)&wt[f0]     = *(const float4*)src;
        *(float4*)&wt[f0 + 4] = *(const float4*)(src + 4);
    }
    __syncthreads();
    float a0 = 0.f, a1 = 0.f, a2 = 0.f, a3 = 0.f;
    const int kb = wv << 7;   // 128-k slice per wave
    #pragma unroll 4
    for (int kl = 0; kl < 128; kl += 4) {
        const int k = kb + kl;
        const float4 xv = *(const float4*)(h1PK + ((k >> 2) << 8) + (lane << 2));
        const float4 w0 = *(const float4*)&wt[k];
        const float4 w1 = *(const float4*)&wt[1024 + k];
        const float4 w2 = *(const float4*)&wt[2048 + k];
        const float4 w3 = *(const float4*)&wt[3072 + k];
        a0 = fmaf(w0.x, xv.x, a0); a0 = fmaf(w0.y, xv.y, a0);
        a0 = fmaf(w0.z, xv.z, a0); a0 = fmaf(w0.w, xv.w, a0);
        a1 = fmaf(w1.x, xv.x, a1); a1 = fmaf(w1.y, xv.y, a1);
        a1 = fmaf(w1.z, xv.z, a1); a1 = fmaf(w1.w, xv.w, a1);
        a2 = fmaf(w2.x, xv.x, a2); a2 = fmaf(w2.y, xv.y, a2);
        a2 = fmaf(w2.z, xv.z, a2); a2 = fmaf(w2.w, xv.w, a2);
        a3 = fmaf(w3.x, xv.x, a3); a3 = fmaf(w3.y, xv.y, a3);
        a3 = fmaf(w3.z, xv.z, a3); a3 = fmaf(w3.w, xv.w, a3);
    }
    zb[(wv << 8) + (0 << 6) + lane] = a0;
    zb[(wv << 8) + (1 << 6) + lane] = a1;
    zb[(wv << 8) + (2 << 6) + lane] = a2;
    zb[(wv << 8) + (3 << 6) + lane] = a3;
    __syncthreads();
    if (tid < 256) {
        const int r = tid >> 6, b = tid & 63;
        float s = linb[hu0 + r];
        #pragma unroll
        for (int w = 0; w < 8; ++w) s += zb[(w << 8) + (r << 6) + b];
        logits[((hu0 + r) << 6) + b] = s;
    }
}

// per-batch-row log-softmax + greedy argmax + masked NLL. blocks 0..63 active.
__device__ __forceinline__ void softmax_phase(
    float* __restrict__ smem_f, int* __restrict__ smem_i, int t,
    const float* __restrict__ logits, const int* __restrict__ tag_ids,
    float* __restrict__ out, int* __restrict__ deint, float* __restrict__ loss)
{
    if (blockIdx.x >= Bz) return;
    const int b = blockIdx.x, tid = threadIdx.x;
    float* s_v = smem_f;          // [512]
    float* s_r = smem_f + 512;    // [512]
    float* s_tgt = smem_f + 1024; // [1]
    int*   s_i = smem_i;          // [512]

    const float v0 = logits[(tid << 6) + b];
    const float v1 = logits[((tid + 512) << 6) + b];

    float bv = v0; int bi = tid;
    if (v1 > bv) { bv = v1; bi = tid + 512; }
    s_v[tid] = bv; s_i[tid] = bi;
    __syncthreads();
    for (int s = 256; s > 0; s >>= 1) {
        if (tid < s) {
            const float v2 = s_v[tid + s]; const int i2 = s_i[tid + s];
            if (v2 > s_v[tid] || (v2 == s_v[tid] && i2 < s_i[tid])) {
                s_v[tid] = v2; s_i[tid] = i2;
            }
        }
        __syncthreads();
    }
    const float gmax = s_v[0];
    const int   gam  = s_i[0];

    s_r[tid] = expf(v0 - gmax) + expf(v1 - gmax);
    const int tgt = tag_ids[b * TLz + t];
    if (tid == tgt) s_tgt[0] = v0;          // tgt < 74 < 512
    __syncthreads();
    for (int s = 256; s > 0; s >>= 1) {
        if (tid < s) s_r[tid] += s_r[tid + s];
        __syncthreads();
    }
    const float lse = gmax + logf(s_r[0]);

    float* orow = out + (((size_t)t * Bz + b) << 10);
    orow[tid]       = v0 - lse;
    orow[tid + 512] = v1 - lse;

    if (tid == 0) {
        deint[b] = gam;
        if (tgt != 0) {   // PAD == 0
            int cnt = 0;
            for (int bb = 0; bb < Bz; ++bb)
                cnt += (tag_ids[bb * TLz + t] != 0) ? 1 : 0;
            if (cnt < 1) cnt = 1;
            atomicAdd(loss, (lse - s_tgt[0]) / (float)cnt);
        }
    }
    __syncthreads();
}

__global__ void __launch_bounds__(TPB) seq2seq_kernel(
    const int* __restrict__ input_ids, const int* __restrict__ tag_ids,
    const float* __restrict__ enc_embed,
    const float* __restrict__ eW0, const float* __restrict__ eU0, const float* __restrict__ eb0,
    const float* __restrict__ eW1, const float* __restrict__ eU1, const float* __restrict__ eb1,
    const float* __restrict__ dec_embed,
    const float* __restrict__ dW0, const float* __restrict__ dU0, const float* __restrict__ db0,
    const float* __restrict__ dW1, const float* __restrict__ dU1, const float* __restrict__ db1,
    const float* __restrict__ linW, const float* __restrict__ linb,
    float* __restrict__ out, float* __restrict__ wsf)
{
    cg::grid_group grid = cg::this_grid();
    __shared__ float smem_f[6144];
    __shared__ int   smem_i[512];

    // ws layout (floats); h buffers are 4-k-packed [256][64][4]
    float* h0a = wsf;                 // 65536
    float* h0b = wsf + 65536;
    float* h1a = wsf + 131072;
    float* h1b = wsf + 196608;
    float* c0  = wsf + 262144;        // [1024][64]
    float* c1  = wsf + 327680;
    float* logits = wsf + 393216;     // [1024][64]
    int*   deint  = (int*)(wsf + 458752);
    float* loss   = out + (size_t)TLz * Bz * Hz;

    {
        const int gsz = NBLK * TPB;
        for (int i = blockIdx.x * TPB + threadIdx.x; i < 458752 + Bz; i += gsz) {
            if (i < 458752) wsf[i] = 0.0f;
            else            deint[i - 458752] = 0;
        }
        if (blockIdx.x == 0 && threadIdx.x == 0) *loss = 0.0f;
    }
    grid.sync();

    float* h0c = h0a; float* h0n = h0b;
    float* h1c = h1a; float* h1n = h1b;

    // ---------------- encoder ----------------
    for (int t = 0; t < SLz; ++t) {
        lstm_phase(smem_f, enc_embed, input_ids, SLz, t, nullptr, Ez,
                   eW0, eU0, eb0, h0c, h0n, c0);
        grid.sync();
        lstm_phase(smem_f, nullptr, nullptr, 0, 0, h0n, Hz,
                   eW1, eU1, eb1, h1c, h1n, c1);
        grid.sync();
        float* tmp = h0c; h0c = h0n; h0n = tmp;
        tmp = h1c; h1c = h1n; h1n = tmp;
    }

    // ---------------- decoder ----------------
    for (int t = 0; t < TLz; ++t) {
        lstm_phase(smem_f, dec_embed, deint, 1, 0, nullptr, Ez,
                   dW0, dU0, db0, h0c, h0n, c0);
        grid.sync();
        lstm_phase(smem_f, nullptr, nullptr, 0, 0, h0n, Hz,
                   dW1, dU1, db1, h1c, h1n, c1);
        grid.sync();
        head_phase(smem_f, linW, linb, h1n, logits);
        grid.sync();
        softmax_phase(smem_f, smem_i, t, logits, tag_ids, out, deint, loss);
        grid.sync();
        float* tmp = h0c; h0c = h0n; h0n = tmp;
        tmp = h1c; h1c = h1n; h1n = tmp;
    }
}

extern "C" void kernel_launch(void* const* d_in, const int* in_sizes, int n_in,
                              void* d_out, int out_size, void* d_ws, size_t ws_size,
                              hipStream_t stream) {
    const int*   input_ids = (const int*)d_in[0];
    const int*   tag_ids   = (const int*)d_in[1];
    const float* enc_embed = (const float*)d_in[2];
    const float* eW0 = (const float*)d_in[3];
    const float* eU0 = (const float*)d_in[4];
    const float* eb0 = (const float*)d_in[5];
    const float* eW1 = (const float*)d_in[6];
    const float* eU1 = (const float*)d_in[7];
    const float* eb1 = (const float*)d_in[8];
    const float* dec_embed = (const float*)d_in[9];
    const float* dW0 = (const float*)d_in[10];
    const float* dU0 = (const float*)d_in[11];
    const float* db0 = (const float*)d_in[12];
    const float* dW1 = (const float*)d_in[13];
    const float* dU1 = (const float*)d_in[14];
    const float* db1 = (const float*)d_in[15];
    const float* linW = (const float*)d_in[16];
    const float* linb = (const float*)d_in[17];
    float* out = (float*)d_out;
    float* wsf = (float*)d_ws;

    void* args[] = { &input_ids, &tag_ids, &enc_embed,
                     &eW0, &eU0, &eb0, &eW1, &eU1, &eb1,
                     &dec_embed, &dW0, &dU0, &db0, &dW1, &dU1, &db1,
                     &linW, &linb, &out, &wsf };
    (void)hipLaunchCooperativeKernel(seq2seq_kernel, dim3(NBLK), dim3(TPB),
                                     args, 0u, stream);
}